// Round 3
// baseline (220.363 us; speedup 1.0000x reference)
//
#include <hip/hip_runtime.h>

// out[e,i] = sum_j mat[e,i,j] v[e,j] + bias[e,i],  [mat|bias] = MLP(pos).reshape(32,33)
// R3: P[e,col] = h2[e,:128] @ Wpack[:,col] (col=j*32+i) via MFMA with A(h2)-frags resident
// in VGPRs; einsum fused as per-tile FMA vs LDS-resident vt; b3 folded via mini-GEMM C-init.
// G-loop reads B-frags DIRECTLY from global (L1/L2-resident 264 KB) -- zero barriers,
// loads stay in flight (no vmcnt(0) drain). LDS = 36.9 KB (vt overlaid on h1c/h2n).
// ws: Wg2 @0 (270336 B), W2f @270336 (32768), b3f @303104 (2048), b3c @305152 (128)

#define E_TOTAL 262144
#define EPB 256
#define NBLK (E_TOTAL / EPB)

typedef float f32x4 __attribute__((ext_vector_type(4)));
typedef short s8v  __attribute__((ext_vector_type(8)));

__device__ __forceinline__ unsigned short f2bf(float x) {
  unsigned u = __float_as_uint(x);
  u += 0x7fffu + ((u >> 16) & 1u);
  return (unsigned short)(u >> 16);
}

// ---------------- prep: pack W2/W3/b3 into MFMA B-fragment order ----------------
__global__ void prep_pack(const float* __restrict__ W2, const float* __restrict__ W3,
                          const float* __restrict__ b3,
                          unsigned short* __restrict__ Wg2, unsigned short* __restrict__ W2f,
                          unsigned short* __restrict__ b3f, float* __restrict__ b3c) {
  int idx = blockIdx.x * 256 + threadIdx.x;   // 528 blocks cover 135168
  if (idx < 135168) {
    // Wg2[((nn*4+ks)*64 + lane)*8 + jj] : B[k=ks*32+(lane>>4)*8+jj][col=nnt*16+(lane&15)]
    // permuted tile order: nn<33 -> nnt=2*nn (ih=0, j=nn), else nnt=2*(nn-33)+1 (ih=1)
    int jj = idx & 7, lane = (idx >> 3) & 63;
    int ksnn = idx >> 9, ks = ksnn & 3, nn = ksnn >> 2;
    int nnt = (nn < 33) ? (2 * nn) : (2 * (nn - 33) + 1);
    int k = ks * 32 + ((lane >> 4) << 3) + jj;
    int col = nnt * 16 + (lane & 15);        // col = j*32 + i
    int i = col & 31, j = col >> 5;
    Wg2[idx] = f2bf(W3[k * 1056 + i * 33 + j]);
  }
  if (idx < 16384) {
    int ks = idx >> 12, nt = (idx >> 9) & 7, l = (idx >> 3) & 63, jj = idx & 7;
    int k = ks * 32 + ((l >> 4) << 3) + jj;
    int n = nt * 16 + (l & 15);
    W2f[idx] = f2bf(W2[k * 128 + n]);
  }
  if (idx < 1024) {
    int jj = idx & 7, lane = (idx >> 3) & 63, ih = idx >> 9;
    int j = ((lane >> 4) << 3) + jj, i = ih * 16 + (lane & 15);
    b3f[idx] = f2bf(b3[i * 33 + j]);
  }
  if (idx < 32) b3c[idx] = b3[idx * 33 + 32];
}

// ---------------- one G-tile: 16 MFMA + fused einsum FMA ----------------
template <int IH>
__device__ __forceinline__ void g_tile(const s8v (&bfr)[4], const float* __restrict__ vt,
                                       int j, int eoff,
                                       const s8v (&af)[4][4], float (&oa)[2][4][4]) {
  const f32x4 zero4 = {0.f, 0.f, 0.f, 0.f};
  f32x4 p[4];
#pragma unroll
  for (int m = 0; m < 4; ++m)
    p[m] = __builtin_amdgcn_mfma_f32_16x16x32_bf16(af[m][0], bfr[0], zero4, 0, 0, 0);
#pragma unroll
  for (int ks = 1; ks < 4; ++ks)
#pragma unroll
    for (int m = 0; m < 4; ++m)
      p[m] = __builtin_amdgcn_mfma_f32_16x16x32_bf16(af[m][ks], bfr[ks], p[m], 0, 0, 0);
  const float* vp = vt + j * 260 + eoff;
#pragma unroll
  for (int m = 0; m < 4; ++m) {
    f32x4 vv = *(const f32x4*)(vp + m * 16);
#pragma unroll
    for (int r = 0; r < 4; ++r) oa[IH][m][r] += vv[r] * p[m][r];
  }
}

// ---------------- G-pass over 33 tiles of one ih half (no barriers) ----------------
template <int IH>
__device__ __forceinline__ void g_pass(const unsigned short* __restrict__ Wg2,
                                       const float* __restrict__ vt,
                                       int lane, int eoff,
                                       const s8v (&af)[4][4], float (&oa)[2][4][4]) {
  const unsigned short* base = Wg2 + IH * 33 * 2048 + lane * 8;
  s8v bnx[4];
#pragma unroll
  for (int ks = 0; ks < 4; ++ks) bnx[ks] = *(const s8v*)(base + ks * 512);
  for (int j = 0; j < 32; ++j) {
    s8v bfr[4];
#pragma unroll
    for (int ks = 0; ks < 4; ++ks) bfr[ks] = bnx[ks];
#pragma unroll
    for (int ks = 0; ks < 4; ++ks)
      bnx[ks] = *(const s8v*)(base + (j + 1) * 2048 + ks * 512);
    g_tile<IH>(bfr, vt, j, eoff, af, oa);
  }
  g_tile<IH>(bnx, vt, 32, eoff, af, oa);
}

// ---------------- fused main kernel ----------------
// 256 threads (4 waves), 256 edges/block; wave w owns edges [B0+w*64, B0+w*64+64).
// LDS 36864 B: transient h1c u16[64][144] @0, h2n u16[64][144] @18432;
// vt f32[33][260] @0 (34320) overlaid after stages 1+2 die.
__global__ __launch_bounds__(256, 2) void fnn_fused(
    const float* __restrict__ pos_i, const float* __restrict__ pos_j,
    const float* __restrict__ vj, const float* __restrict__ W1,
    const float* __restrict__ b1, const float* __restrict__ b2,
    const unsigned short* __restrict__ W2f, const unsigned short* __restrict__ Wg2,
    const unsigned short* __restrict__ b3f, const float* __restrict__ b3c,
    float* __restrict__ out) {
  __shared__ __attribute__((aligned(16))) char smem[36864];
  float* vt = (float*)smem;                               // [33][260] f32
  unsigned short* h1c = (unsigned short*)smem;            // [64][144] u16
  unsigned short* h2n = (unsigned short*)(smem + 18432);  // [64][144] u16

  const int tid = threadIdx.x;
  const int w = tid >> 6, lane = tid & 63, q = lane >> 4, ln = lane & 15;
  const int B0 = blockIdx.x * EPB;
  const int eoff = w * 64 + q * 4;

  // --- out-acc init via b3 mini-GEMM: oa = sum_j v[e,j] b3[i*33+j] + b3[i*33+32] ---
  float oa[2][4][4];
  {
    s8v av[4];
#pragma unroll
    for (int m = 0; m < 4; ++m) {
      int e = B0 + w * 64 + m * 16 + ln;
      const float4 va = *(const float4*)(vj + (size_t)e * 32 + q * 8);
      const float4 vb = *(const float4*)(vj + (size_t)e * 32 + q * 8 + 4);
      s8v t;
      t[0] = (short)f2bf(va.x); t[1] = (short)f2bf(va.y);
      t[2] = (short)f2bf(va.z); t[3] = (short)f2bf(va.w);
      t[4] = (short)f2bf(vb.x); t[5] = (short)f2bf(vb.y);
      t[6] = (short)f2bf(vb.z); t[7] = (short)f2bf(vb.w);
      av[m] = t;
    }
#pragma unroll
    for (int ih = 0; ih < 2; ++ih) {
      s8v b3fr = *(const s8v*)(b3f + (ih * 64 + lane) * 8);
      float cbv = b3c[ih * 16 + ln];
      f32x4 ci = {cbv, cbv, cbv, cbv};
#pragma unroll
      for (int m = 0; m < 4; ++m) {
        f32x4 p = __builtin_amdgcn_mfma_f32_16x16x32_bf16(av[m], b3fr, ci, 0, 0, 0);
#pragma unroll
        for (int r = 0; r < 4; ++r) oa[ih][m][r] = p[r];
      }
    }
  }

  // --- W1/b1/b2 register slices ---
  const int hh0 = (tid & 15) * 8;
  float w1r[4][8], b1r[8], b2r[8];
#pragma unroll
  for (int d = 0; d < 4; ++d)
#pragma unroll
    for (int u = 0; u < 8; ++u) w1r[d][u] = W1[d * 128 + hh0 + u];
#pragma unroll
  for (int u = 0; u < 8; ++u) b1r[u] = b1[hh0 + u];
#pragma unroll
  for (int nt = 0; nt < 8; ++nt) b2r[nt] = b2[nt * 16 + ln];

  // --- stages 1+2 per quarter (64 edges); wave qtr extracts its A-frags ---
  s8v af[4][4];
  for (int qtr = 0; qtr < 4; ++qtr) {
    // stage 1: h1 = relu(pos @ W1 + b1) for 64 edges; thread owns 8 cols x 4 rows
#pragma unroll
    for (int half = 0; half < 4; ++half) {
      int ee = (tid >> 4) + half * 16;       // 0..63
      int eg = B0 + qtr * 64 + ee;
      float2 pi = *(const float2*)(pos_i + (size_t)eg * 2);
      float2 pj = *(const float2*)(pos_j + (size_t)eg * 2);
      s8v hv;
#pragma unroll
      for (int u = 0; u < 8; ++u) {
        float o = b1r[u] + pi.x * w1r[0][u] + pi.y * w1r[1][u] +
                  pj.x * w1r[2][u] + pj.y * w1r[3][u];
        hv[u] = (short)f2bf(fmaxf(o, 0.f));
      }
      *(s8v*)&h1c[ee * 144 + hh0] = hv;
    }
    __syncthreads();
    // stage 2: h2 = relu(h1 @ W2 + b2); wave w owns edge rows w*16..w*16+15 (8 nt tiles)
    {
      s8v afr[4];
#pragma unroll
      for (int ks = 0; ks < 4; ++ks)
        afr[ks] = *(const s8v*)&h1c[(w * 16 + ln) * 144 + ks * 32 + q * 8];
#pragma unroll
      for (int nt = 0; nt < 8; ++nt) {
        f32x4 a4 = {0.f, 0.f, 0.f, 0.f};
#pragma unroll
        for (int ks = 0; ks < 4; ++ks) {
          s8v bfr2 = *(const s8v*)(W2f + ((ks * 8 + nt) * 64 + lane) * 8);
          a4 = __builtin_amdgcn_mfma_f32_16x16x32_bf16(afr[ks], bfr2, a4, 0, 0, 0);
        }
#pragma unroll
        for (int r = 0; r < 4; ++r)
          h2n[(w * 16 + q * 4 + r) * 144 + nt * 16 + ln] =
              f2bf(fmaxf(a4[r] + b2r[nt], 0.f));
      }
    }
    __syncthreads();
    if (w == qtr) {
#pragma unroll
      for (int m = 0; m < 4; ++m)
#pragma unroll
        for (int ks = 0; ks < 4; ++ks)
          af[m][ks] = *(const s8v*)&h2n[(m * 16 + ln) * 144 + ks * 32 + q * 8];
    }
    // extract overlaps next stage-1 (h1c disjoint from h2n); next barrier guards h2n reuse
  }
  __syncthreads();   // last extract drained before vt overlays h1c/h2n

  // --- build vt: vt[j][e] = v[e,j] f32, row 32 = 1.0 ---
  {
    const float* vrow = vj + (size_t)(B0 + tid) * 32;
#pragma unroll
    for (int j4 = 0; j4 < 8; ++j4) {
      float4 vv = *(const float4*)(vrow + j4 * 4);
      vt[(j4 * 4 + 0) * 260 + tid] = vv.x;
      vt[(j4 * 4 + 1) * 260 + tid] = vv.y;
      vt[(j4 * 4 + 2) * 260 + tid] = vv.z;
      vt[(j4 * 4 + 3) * 260 + tid] = vv.w;
    }
    vt[32 * 260 + tid] = 1.0f;
  }
  __syncthreads();

  // --- G-loop: 66 tiles, B-frags straight from global (L1/L2), ZERO barriers ---
  g_pass<0>(Wg2, vt, lane, eoff, af, oa);
  g_pass<1>(Wg2, vt, lane, eoff, af, oa);

  // --- epilogue: out[e,i] f32 ---
#pragma unroll
  for (int m = 0; m < 4; ++m)
#pragma unroll
    for (int ih = 0; ih < 2; ++ih)
#pragma unroll
      for (int r = 0; r < 4; ++r) {
        int e = B0 + w * 64 + m * 16 + q * 4 + r;
        out[(size_t)e * 32 + ih * 16 + ln] = oa[ih][m][r];
      }
}

extern "C" void kernel_launch(void* const* d_in, const int* in_sizes, int n_in,
                              void* d_out, int out_size, void* d_ws, size_t ws_size,
                              hipStream_t stream) {
  const float* pos_i = (const float*)d_in[0];
  const float* pos_j = (const float*)d_in[1];
  const float* vj    = (const float*)d_in[2];
  const float* W1    = (const float*)d_in[3];
  const float* b1    = (const float*)d_in[4];
  const float* W2    = (const float*)d_in[5];
  const float* b2    = (const float*)d_in[6];
  const float* W3    = (const float*)d_in[7];
  const float* b3    = (const float*)d_in[8];
  float* outp = (float*)d_out;

  unsigned short* Wg2 = (unsigned short*)d_ws;
  unsigned short* W2f = (unsigned short*)((char*)d_ws + 270336);
  unsigned short* b3f = (unsigned short*)((char*)d_ws + 303104);
  float*          b3c = (float*)((char*)d_ws + 305152);

  prep_pack<<<528, 256, 0, stream>>>(W2, W3, b3, Wg2, W2f, b3f, b3c);
  fnn_fused<<<NBLK, 256, 0, stream>>>(pos_i, pos_j, vj, W1, b1, b2, W2f, Wg2, b3f, b3c, outp);
}

// Round 4
// 218.922 us; speedup vs baseline: 1.0066x; 1.0066x over previous
//
#include <hip/hip_runtime.h>

// out[e,i] = sum_j mat[e,i,j] v[e,j] + bias[e,i],  [mat|bias] = MLP(pos).reshape(32,33)
// R4: P[e,col] = h2[e,:128] @ Wpack[:,col] (col=j*32+i) via MFMA, A(h2)-frags VGPR-resident,
// einsum fused as per-tile FMA vs LDS-resident vt (f32, broadcast reads); b3 via mini-GEMM C-init.
// B staged global->LDS with __builtin_amdgcn_global_load_lds (16B DMA, no VGPR roundtrip),
// double-buffered 3-tile chunks, 22 barriers total. LDS 58368 B -> 2 blocks/CU.
// ws: Wg2 @0 (270336 B), W2f @270336 (32768), b3f @303104 (2048), b3c @305152 (128)

#define E_TOTAL 262144
#define EPB 256
#define NBLK (E_TOTAL / EPB)

typedef float f32x4 __attribute__((ext_vector_type(4)));
typedef short s8v  __attribute__((ext_vector_type(8)));

__device__ __forceinline__ unsigned short f2bf(float x) {
  unsigned u = __float_as_uint(x);
  u += 0x7fffu + ((u >> 16) & 1u);
  return (unsigned short)(u >> 16);
}

__device__ __forceinline__ void gld16(const void* g, void* l) {
  __builtin_amdgcn_global_load_lds(
      (const __attribute__((address_space(1))) unsigned int*)g,
      (__attribute__((address_space(3))) unsigned int*)l, 16, 0, 0);
}

// ---------------- prep: pack W2/W3/b3 into MFMA B-fragment order ----------------
__global__ void prep_pack(const float* __restrict__ W2, const float* __restrict__ W3,
                          const float* __restrict__ b3,
                          unsigned short* __restrict__ Wg2, unsigned short* __restrict__ W2f,
                          unsigned short* __restrict__ b3f, float* __restrict__ b3c) {
  int idx = blockIdx.x * 256 + threadIdx.x;   // 528 blocks cover 135168
  if (idx < 135168) {
    // Wg2[((nn*4+ks)*64 + lane)*8 + jj] : B[k=ks*32+(lane>>4)*8+jj][col=nnt*16+(lane&15)]
    // permuted tile order: nn<33 -> nnt=2*nn (ih=0, j=nn), else nnt=2*(nn-33)+1 (ih=1)
    int jj = idx & 7, lane = (idx >> 3) & 63;
    int ksnn = idx >> 9, ks = ksnn & 3, nn = ksnn >> 2;
    int nnt = (nn < 33) ? (2 * nn) : (2 * (nn - 33) + 1);
    int k = ks * 32 + ((lane >> 4) << 3) + jj;
    int col = nnt * 16 + (lane & 15);        // col = j*32 + i
    int i = col & 31, j = col >> 5;
    Wg2[idx] = f2bf(W3[k * 1056 + i * 33 + j]);
  }
  if (idx < 16384) {
    int ks = idx >> 12, nt = (idx >> 9) & 7, l = (idx >> 3) & 63, jj = idx & 7;
    int k = ks * 32 + ((l >> 4) << 3) + jj;
    int n = nt * 16 + (l & 15);
    W2f[idx] = f2bf(W2[k * 128 + n]);
  }
  if (idx < 1024) {
    int jj = idx & 7, lane = (idx >> 3) & 63, ih = idx >> 9;
    int j = ((lane >> 4) << 3) + jj, i = ih * 16 + (lane & 15);
    b3f[idx] = f2bf(b3[i * 33 + j]);
  }
  if (idx < 32) b3c[idx] = b3[idx * 33 + 32];
}

// ---------------- one 3-tile chunk of the G-loop (IH compile-time) ----------------
template <int IH>
__device__ __forceinline__ void g_chunk(const unsigned short* __restrict__ buf,
                                        const float* __restrict__ vt,
                                        int j0, int lane, int eoff,
                                        const s8v (&af)[4][4], float (&oa)[2][4][4]) {
  const f32x4 zero4 = {0.f, 0.f, 0.f, 0.f};
#pragma unroll
  for (int t = 0; t < 3; ++t) {
    s8v bfr[4];
#pragma unroll
    for (int ks = 0; ks < 4; ++ks)
      bfr[ks] = *(const s8v*)&buf[t * 2048 + ks * 512 + lane * 8];
    f32x4 p[4];
#pragma unroll
    for (int m = 0; m < 4; ++m)
      p[m] = __builtin_amdgcn_mfma_f32_16x16x32_bf16(af[m][0], bfr[0], zero4, 0, 0, 0);
#pragma unroll
    for (int ks = 1; ks < 4; ++ks)
#pragma unroll
      for (int m = 0; m < 4; ++m)
        p[m] = __builtin_amdgcn_mfma_f32_16x16x32_bf16(af[m][ks], bfr[ks], p[m], 0, 0, 0);
    const float* vp = vt + (j0 + t) * 256 + eoff;
#pragma unroll
    for (int m = 0; m < 4; ++m) {
      f32x4 vv = *(const f32x4*)(vp + m * 16);
#pragma unroll
      for (int r = 0; r < 4; ++r) oa[IH][m][r] += vv[r] * p[m][r];
    }
  }
}

// ---------------- fused main kernel ----------------
// 256 threads (4 waves), 256 edges/block; wave w owns edges [B0+w*64, B0+w*64+64).
// LDS 58368 B: vt f32[33][256] @0 (33792) + Bb u16[2][6144] @33792 (24576).
// Stage overlay: h1c u16[64][144] @0 (18432), h2n u16[64][144] @18432 (->36864).
__global__ __launch_bounds__(256, 2) void fnn_fused(
    const float* __restrict__ pos_i, const float* __restrict__ pos_j,
    const float* __restrict__ vj, const float* __restrict__ W1,
    const float* __restrict__ b1, const float* __restrict__ b2,
    const unsigned short* __restrict__ W2f, const unsigned short* __restrict__ Wg2,
    const unsigned short* __restrict__ b3f, const float* __restrict__ b3c,
    float* __restrict__ out) {
  __shared__ __attribute__((aligned(16))) char smem[58368];
  float* vt = (float*)smem;                               // [33][256] f32
  unsigned short* Bb  = (unsigned short*)(smem + 33792);  // [2][6144] u16
  unsigned short* h1c = (unsigned short*)smem;            // [64][144] u16 (transient)
  unsigned short* h2n = (unsigned short*)(smem + 18432);  // [64][144] u16 (transient)

  const int tid = threadIdx.x;
  const int w = tid >> 6, lane = tid & 63, q = lane >> 4, ln = lane & 15;
  const int B0 = blockIdx.x * EPB;
  const int eoff = w * 64 + q * 4;

  // --- out-acc init via b3 mini-GEMM: oa = sum_j v[e,j] b3[i*33+j] + b3[i*33+32] ---
  float oa[2][4][4];
  {
    s8v av[4];
#pragma unroll
    for (int m = 0; m < 4; ++m) {
      int e = B0 + w * 64 + m * 16 + ln;
      const float4 va = *(const float4*)(vj + (size_t)e * 32 + q * 8);
      const float4 vb = *(const float4*)(vj + (size_t)e * 32 + q * 8 + 4);
      s8v t;
      t[0] = (short)f2bf(va.x); t[1] = (short)f2bf(va.y);
      t[2] = (short)f2bf(va.z); t[3] = (short)f2bf(va.w);
      t[4] = (short)f2bf(vb.x); t[5] = (short)f2bf(vb.y);
      t[6] = (short)f2bf(vb.z); t[7] = (short)f2bf(vb.w);
      av[m] = t;
    }
#pragma unroll
    for (int ih = 0; ih < 2; ++ih) {
      s8v b3fr = *(const s8v*)(b3f + (ih * 64 + lane) * 8);
      float cbv = b3c[ih * 16 + ln];
      f32x4 ci = {cbv, cbv, cbv, cbv};
#pragma unroll
      for (int m = 0; m < 4; ++m) {
        f32x4 p = __builtin_amdgcn_mfma_f32_16x16x32_bf16(av[m], b3fr, ci, 0, 0, 0);
#pragma unroll
        for (int r = 0; r < 4; ++r) oa[ih][m][r] = p[r];
      }
    }
  }

  // --- W1/b1/b2 register slices ---
  const int hh0 = (tid & 15) * 8;
  float w1r[4][8], b1r[8], b2r[8];
#pragma unroll
  for (int d = 0; d < 4; ++d)
#pragma unroll
    for (int u = 0; u < 8; ++u) w1r[d][u] = W1[d * 128 + hh0 + u];
#pragma unroll
  for (int u = 0; u < 8; ++u) b1r[u] = b1[hh0 + u];
#pragma unroll
  for (int nt = 0; nt < 8; ++nt) b2r[nt] = b2[nt * 16 + ln];

  // --- stages 1+2 per quarter (64 edges); wave qtr extracts its A-frags ---
  s8v af[4][4];
  for (int qtr = 0; qtr < 4; ++qtr) {
#pragma unroll
    for (int half = 0; half < 4; ++half) {
      int ee = (tid >> 4) + half * 16;       // 0..63
      int eg = B0 + qtr * 64 + ee;
      float2 pi = *(const float2*)(pos_i + (size_t)eg * 2);
      float2 pj = *(const float2*)(pos_j + (size_t)eg * 2);
      s8v hv;
#pragma unroll
      for (int u = 0; u < 8; ++u) {
        float o = b1r[u] + pi.x * w1r[0][u] + pi.y * w1r[1][u] +
                  pj.x * w1r[2][u] + pj.y * w1r[3][u];
        hv[u] = (short)f2bf(fmaxf(o, 0.f));
      }
      *(s8v*)&h1c[ee * 144 + hh0] = hv;
    }
    __syncthreads();
    {
      s8v afr[4];
#pragma unroll
      for (int ks = 0; ks < 4; ++ks)
        afr[ks] = *(const s8v*)&h1c[(w * 16 + ln) * 144 + ks * 32 + q * 8];
#pragma unroll
      for (int nt = 0; nt < 8; ++nt) {
        f32x4 a4 = {0.f, 0.f, 0.f, 0.f};
#pragma unroll
        for (int ks = 0; ks < 4; ++ks) {
          s8v bfr2 = *(const s8v*)(W2f + ((ks * 8 + nt) * 64 + lane) * 8);
          a4 = __builtin_amdgcn_mfma_f32_16x16x32_bf16(afr[ks], bfr2, a4, 0, 0, 0);
        }
#pragma unroll
        for (int r = 0; r < 4; ++r)
          h2n[(w * 16 + q * 4 + r) * 144 + nt * 16 + ln] =
              f2bf(fmaxf(a4[r] + b2r[nt], 0.f));
      }
    }
    __syncthreads();
    if (w == qtr) {
#pragma unroll
      for (int m = 0; m < 4; ++m)
#pragma unroll
        for (int ks = 0; ks < 4; ++ks)
          af[m][ks] = *(const s8v*)&h2n[(m * 16 + ln) * 144 + ks * 32 + q * 8];
    }
    // extraction overlaps next stage-1 (h1c disjoint from h2n); barrier guards h2n reuse
  }
  __syncthreads();   // last extract drained before vt/Bb overlay h1c/h2n

  // --- build vt: vt[j][e] = v[e,j] f32, row 32 = 1.0 ---
  {
    const float* vrow = vj + (size_t)(B0 + tid) * 32;
#pragma unroll
    for (int j4 = 0; j4 < 8; ++j4) {
      float4 vv = *(const float4*)(vrow + j4 * 4);
      vt[(j4 * 4 + 0) * 256 + tid] = vv.x;
      vt[(j4 * 4 + 1) * 256 + tid] = vv.y;
      vt[(j4 * 4 + 2) * 256 + tid] = vv.z;
      vt[(j4 * 4 + 3) * 256 + tid] = vv.w;
    }
    vt[32 * 256 + tid] = 1.0f;
  }

  // --- preload B chunk 0 via LDS-DMA (wave-uniform base + lane*16) ---
  {
    const char* g = (const char*)Wg2 + tid * 16;
    char* l = (char*)Bb + (tid & 192) * 16;   // w*1024
#pragma unroll
    for (int t = 0; t < 3; ++t) gld16(g + t * 4096, l + t * 4096);
  }
  __syncthreads();

  // --- G-loop: 22 chunks x 3 tiles, double-buffered DMA staging ---
  for (int c = 0; c < 22; ++c) {
    const unsigned short* buf = Bb + (c & 1) * 6144;
    if (c + 1 < 22) {
      const char* g = (const char*)Wg2 + (c + 1) * 12288 + tid * 16;
      char* l = (char*)Bb + ((c + 1) & 1) * 12288 + (tid & 192) * 16;
#pragma unroll
      for (int t = 0; t < 3; ++t) gld16(g + t * 4096, l + t * 4096);
    }
    if (c < 11) g_chunk<0>(buf, vt, c * 3, lane, eoff, af, oa);
    else        g_chunk<1>(buf, vt, (c - 11) * 3, lane, eoff, af, oa);
    __syncthreads();
  }

  // --- epilogue: out[e,i] f32 ---
#pragma unroll
  for (int m = 0; m < 4; ++m)
#pragma unroll
    for (int ih = 0; ih < 2; ++ih)
#pragma unroll
      for (int r = 0; r < 4; ++r) {
        int e = B0 + w * 64 + m * 16 + q * 4 + r;
        out[(size_t)e * 32 + ih * 16 + ln] = oa[ih][m][r];
      }
}

extern "C" void kernel_launch(void* const* d_in, const int* in_sizes, int n_in,
                              void* d_out, int out_size, void* d_ws, size_t ws_size,
                              hipStream_t stream) {
  const float* pos_i = (const float*)d_in[0];
  const float* pos_j = (const float*)d_in[1];
  const float* vj    = (const float*)d_in[2];
  const float* W1    = (const float*)d_in[3];
  const float* b1    = (const float*)d_in[4];
  const float* W2    = (const float*)d_in[5];
  const float* b2    = (const float*)d_in[6];
  const float* W3    = (const float*)d_in[7];
  const float* b3    = (const float*)d_in[8];
  float* outp = (float*)d_out;

  unsigned short* Wg2 = (unsigned short*)d_ws;
  unsigned short* W2f = (unsigned short*)((char*)d_ws + 270336);
  unsigned short* b3f = (unsigned short*)((char*)d_ws + 303104);
  float*          b3c = (float*)((char*)d_ws + 305152);

  prep_pack<<<528, 256, 0, stream>>>(W2, W3, b3, Wg2, W2f, b3f, b3c);
  fnn_fused<<<NBLK, 256, 0, stream>>>(pos_i, pos_j, vj, W1, b1, b2, W2f, Wg2, b3f, b3c, outp);
}

// Round 5
// 189.198 us; speedup vs baseline: 1.1647x; 1.1571x over previous
//
#include <hip/hip_runtime.h>

// out[e,i] = sum_j mat[e,i,j] v[e,j] + bias[e,i],  [mat|bias] = MLP(pos).reshape(32,33)
// R5 = R2 topology (110 us, VGPR 120, clean counters) with ONE change: B staging via
// __builtin_amdgcn_global_load_lds 16B DMA (no VGPR roundtrip, pre[] registers deleted).
// P[e,col] = h2[e,:128] @ Wpack[:,col] (col=j*32+i) via MFMA, A(h2)-frags VGPR-resident;
// einsum fused as per-tile FMA vs LDS vt; b3 folded via mini-GEMM C-init.
// ws: Wg2 @0 (270336 B), W2f @270336 (32768), b3f @303104 (2048), b3c @305152 (128)

#define E_TOTAL 262144
#define EPB 256
#define NBLK (E_TOTAL / EPB)

typedef float f32x4 __attribute__((ext_vector_type(4)));
typedef short s8v  __attribute__((ext_vector_type(8)));

__device__ __forceinline__ unsigned short f2bf(float x) {
  unsigned u = __float_as_uint(x);
  u += 0x7fffu + ((u >> 16) & 1u);
  return (unsigned short)(u >> 16);
}

__device__ __forceinline__ void gld16(const void* g, void* l) {
  __builtin_amdgcn_global_load_lds(
      (const __attribute__((address_space(1))) unsigned int*)g,
      (__attribute__((address_space(3))) unsigned int*)l, 16, 0, 0);
}

// ---------------- prep: pack W2/W3/b3 into MFMA B-fragment order ----------------
__global__ void prep_pack(const float* __restrict__ W2, const float* __restrict__ W3,
                          const float* __restrict__ b3,
                          unsigned short* __restrict__ Wg2, unsigned short* __restrict__ W2f,
                          unsigned short* __restrict__ b3f, float* __restrict__ b3c) {
  int idx = blockIdx.x * 256 + threadIdx.x;   // 528 blocks cover 135168
  if (idx < 135168) {
    // Wg2[((nn*4+ks)*64 + lane)*8 + jj] : B[k=ks*32+(lane>>4)*8+jj][col=nnt*16+(lane&15)]
    // permuted tile order: nn<33 -> nnt=2*nn (ih=0, j=nn), else nnt=2*(nn-33)+1 (ih=1)
    int jj = idx & 7, lane = (idx >> 3) & 63;
    int ksnn = idx >> 9, ks = ksnn & 3, nn = ksnn >> 2;
    int nnt = (nn < 33) ? (2 * nn) : (2 * (nn - 33) + 1);
    int k = ks * 32 + ((lane >> 4) << 3) + jj;
    int col = nnt * 16 + (lane & 15);        // col = j*32 + i
    int i = col & 31, j = col >> 5;
    Wg2[idx] = f2bf(W3[k * 1056 + i * 33 + j]);
  }
  if (idx < 16384) {
    int ks = idx >> 12, nt = (idx >> 9) & 7, l = (idx >> 3) & 63, jj = idx & 7;
    int k = ks * 32 + ((l >> 4) << 3) + jj;
    int n = nt * 16 + (l & 15);
    W2f[idx] = f2bf(W2[k * 128 + n]);
  }
  if (idx < 1024) {
    int jj = idx & 7, lane = (idx >> 3) & 63, ih = idx >> 9;
    int j = ((lane >> 4) << 3) + jj, i = ih * 16 + (lane & 15);
    b3f[idx] = f2bf(b3[i * 33 + j]);
  }
  if (idx < 32) b3c[idx] = b3[idx * 33 + 32];
}

// ---------------- G-loop chunk body (IH compile-time: out-acc half) ----------------
template <int IH>
__device__ __forceinline__ void g_chunk(const unsigned short* __restrict__ buf,
                                        const float* __restrict__ vt,
                                        int j0, int lane, int eoff,
                                        const s8v (&af)[4][4], float (&oa)[2][4][4]) {
  const f32x4 zero4 = {0.f, 0.f, 0.f, 0.f};
#pragma unroll
  for (int t = 0; t < 3; ++t) {
    const int j = j0 + t;
    s8v bfr[4];
#pragma unroll
    for (int ks = 0; ks < 4; ++ks)
      bfr[ks] = *(const s8v*)&buf[(t * 4 + ks) * 512 + lane * 8];
    f32x4 p[4];
#pragma unroll
    for (int m = 0; m < 4; ++m) {
      p[m] = __builtin_amdgcn_mfma_f32_16x16x32_bf16(af[m][0], bfr[0], zero4, 0, 0, 0);
#pragma unroll
      for (int ks = 1; ks < 4; ++ks)
        p[m] = __builtin_amdgcn_mfma_f32_16x16x32_bf16(af[m][ks], bfr[ks], p[m], 0, 0, 0);
    }
    const float* vp = vt + j * 260 + eoff;
#pragma unroll
    for (int m = 0; m < 4; ++m) {
      f32x4 vv = *(const f32x4*)(vp + m * 16);
#pragma unroll
      for (int r = 0; r < 4; ++r) oa[IH][m][r] += vv[r] * p[m][r];
    }
  }
}

// ---------------- fused main kernel ----------------
// 256 threads (4 waves), 256 edges/block; wave w owns edges [B0+w*64, B0+w*64+64).
// LDS: vt f32[33][260] @0 (34320) | transient: h2n u16[64][136] @34320 (17408),
//      h1c u16[32][136] @51728 (8704) | Bbuf u16[2][6144] @34320 (24576, reuses h2n/h1c)
// total 60432 B -> 2 blocks/CU -> 2 waves/SIMD.
__global__ __launch_bounds__(256, 2) void fnn_fused(
    const float* __restrict__ pos_i, const float* __restrict__ pos_j,
    const float* __restrict__ vj, const float* __restrict__ W1,
    const float* __restrict__ b1, const float* __restrict__ b2,
    const unsigned short* __restrict__ W2f, const unsigned short* __restrict__ Wg2,
    const unsigned short* __restrict__ b3f, const float* __restrict__ b3c,
    float* __restrict__ out) {
  __shared__ __attribute__((aligned(16))) char smem[60432];
  float* vt = (float*)smem;                                  // [33][260]
  unsigned short* h2n = (unsigned short*)(smem + 34320);     // [64][136]
  unsigned short* h1c = (unsigned short*)(smem + 51728);     // [32][136]
  unsigned short* Bb  = (unsigned short*)(smem + 34320);     // [2][6144]

  const int tid = threadIdx.x;
  const int w = tid >> 6, lane = tid & 63, q = lane >> 4, ln = lane & 15;
  const int B0 = blockIdx.x * EPB;
  const int eoff = w * 64 + q * 4;

  // --- build vt: vt[j][e] = v[e,j] (f32), row 32 = 1.0 ---
  {
    const float* vrow = vj + (size_t)(B0 + tid) * 32;
#pragma unroll
    for (int j4 = 0; j4 < 8; ++j4) {
      float4 vv = *(const float4*)(vrow + j4 * 4);
      vt[(j4 * 4 + 0) * 260 + tid] = vv.x;
      vt[(j4 * 4 + 1) * 260 + tid] = vv.y;
      vt[(j4 * 4 + 2) * 260 + tid] = vv.z;
      vt[(j4 * 4 + 3) * 260 + tid] = vv.w;
    }
    vt[32 * 260 + tid] = 1.0f;
  }

  // --- out-acc init via b3 mini-GEMM: oa[ih][m][r] = sum_j v[e,j] b3[i*33+j] + b3[i*33+32] ---
  float oa[2][4][4];
  {
    s8v av[4];
#pragma unroll
    for (int m = 0; m < 4; ++m) {
      int e = B0 + w * 64 + m * 16 + ln;
      const float4 va = *(const float4*)(vj + (size_t)e * 32 + q * 8);
      const float4 vb = *(const float4*)(vj + (size_t)e * 32 + q * 8 + 4);
      s8v t;
      t[0] = (short)f2bf(va.x); t[1] = (short)f2bf(va.y);
      t[2] = (short)f2bf(va.z); t[3] = (short)f2bf(va.w);
      t[4] = (short)f2bf(vb.x); t[5] = (short)f2bf(vb.y);
      t[6] = (short)f2bf(vb.z); t[7] = (short)f2bf(vb.w);
      av[m] = t;
    }
#pragma unroll
    for (int ih = 0; ih < 2; ++ih) {
      s8v b3fr = *(const s8v*)(b3f + (ih * 64 + lane) * 8);
      float cbv = b3c[ih * 16 + ln];
      f32x4 ci = {cbv, cbv, cbv, cbv};
#pragma unroll
      for (int m = 0; m < 4; ++m) {
        f32x4 p = __builtin_amdgcn_mfma_f32_16x16x32_bf16(av[m], b3fr, ci, 0, 0, 0);
#pragma unroll
        for (int r = 0; r < 4; ++r) oa[ih][m][r] = p[r];
      }
    }
  }

  // --- W1/b1 register slice: thread owns 8 hidden cols for stage 1 ---
  const int hh0 = (tid & 15) * 8;
  float w1r[4][8], b1r[8];
#pragma unroll
  for (int d = 0; d < 4; ++d)
#pragma unroll
    for (int u = 0; u < 8; ++u) w1r[d][u] = W1[d * 128 + hh0 + u];
#pragma unroll
  for (int u = 0; u < 8; ++u) b1r[u] = b1[hh0 + u];

  // --- stages 1+2 per quarter (64 edges), extract A-frags to registers ---
  s8v af[4][4];
  for (int qtr = 0; qtr < 4; ++qtr) {
    for (int cb = 0; cb < 2; ++cb) {
#pragma unroll
      for (int half = 0; half < 2; ++half) {
        int ee = (tid >> 4) + half * 16;
        int eg = B0 + qtr * 64 + cb * 32 + ee;
        float2 pi = *(const float2*)(pos_i + (size_t)eg * 2);
        float2 pj = *(const float2*)(pos_j + (size_t)eg * 2);
        s8v hv;
#pragma unroll
        for (int u = 0; u < 8; ++u) {
          float o = b1r[u] + pi.x * w1r[0][u] + pi.y * w1r[1][u] +
                    pj.x * w1r[2][u] + pj.y * w1r[3][u];
          hv[u] = (short)f2bf(fmaxf(o, 0.f));
        }
        *(s8v*)&h1c[ee * 136 + hh0] = hv;
      }
      __syncthreads();
#pragma unroll
      for (int s = 0; s < 4; ++s) {
        int tt = w * 4 + s, mt = tt >> 3, nt = tt & 7;
        f32x4 a4 = {0.f, 0.f, 0.f, 0.f};
#pragma unroll
        for (int ks = 0; ks < 4; ++ks) {
          s8v afr = *(const s8v*)&h1c[(mt * 16 + ln) * 136 + ks * 32 + q * 8];
          s8v bfr = *(const s8v*)(W2f + ((ks * 8 + nt) * 64 + lane) * 8);
          a4 = __builtin_amdgcn_mfma_f32_16x16x32_bf16(afr, bfr, a4, 0, 0, 0);
        }
        float b2v = b2[nt * 16 + ln];
        int eb = cb * 32 + mt * 16 + q * 4;
        int kc = nt * 16 + ln;
#pragma unroll
        for (int r = 0; r < 4; ++r)
          h2n[(eb + r) * 136 + kc] = f2bf(fmaxf(a4[r] + b2v, 0.f));
      }
      __syncthreads();
    }
    if (w == qtr) {
#pragma unroll
      for (int m = 0; m < 4; ++m)
#pragma unroll
        for (int ks = 0; ks < 4; ++ks)
          af[m][ks] = *(const s8v*)&h2n[(m * 16 + ln) * 136 + ks * 32 + q * 8];
    }
    __syncthreads();   // extraction reads drained before h2n reuse
  }

  // --- preload B chunk 0 via LDS-DMA (wave-uniform base + lane*16) ---
  {
    const char* g = (const char*)Wg2 + tid * 16;
    char* l = (char*)Bb + (tid & 192) * 16;   // w*1024
#pragma unroll
    for (int t = 0; t < 3; ++t) gld16(g + t * 4096, l + t * 4096);
  }
  __syncthreads();

  // --- G-loop: 22 chunks x 3 n-tiles, double-buffered DMA staging ---
  for (int c = 0; c < 22; ++c) {
    const unsigned short* buf = Bb + (c & 1) * 6144;
    if (c + 1 < 22) {
      const char* g = (const char*)Wg2 + (c + 1) * 12288 + tid * 16;
      char* l = (char*)Bb + ((c + 1) & 1) * 12288 + (tid & 192) * 16;
#pragma unroll
      for (int t = 0; t < 3; ++t) gld16(g + t * 4096, l + t * 4096);
    }
    if (c < 11) g_chunk<0>(buf, vt, c * 3, lane, eoff, af, oa);
    else        g_chunk<1>(buf, vt, (c - 11) * 3, lane, eoff, af, oa);
    __syncthreads();
  }

  // --- epilogue: out[e,i] f32 ---
#pragma unroll
  for (int m = 0; m < 4; ++m)
#pragma unroll
    for (int ih = 0; ih < 2; ++ih)
#pragma unroll
      for (int r = 0; r < 4; ++r) {
        int e = B0 + w * 64 + m * 16 + q * 4 + r;
        out[(size_t)e * 32 + ih * 16 + ln] = oa[ih][m][r];
      }
}

extern "C" void kernel_launch(void* const* d_in, const int* in_sizes, int n_in,
                              void* d_out, int out_size, void* d_ws, size_t ws_size,
                              hipStream_t stream) {
  const float* pos_i = (const float*)d_in[0];
  const float* pos_j = (const float*)d_in[1];
  const float* vj    = (const float*)d_in[2];
  const float* W1    = (const float*)d_in[3];
  const float* b1    = (const float*)d_in[4];
  const float* W2    = (const float*)d_in[5];
  const float* b2    = (const float*)d_in[6];
  const float* W3    = (const float*)d_in[7];
  const float* b3    = (const float*)d_in[8];
  float* outp = (float*)d_out;

  unsigned short* Wg2 = (unsigned short*)d_ws;
  unsigned short* W2f = (unsigned short*)((char*)d_ws + 270336);
  unsigned short* b3f = (unsigned short*)((char*)d_ws + 303104);
  float*          b3c = (float*)((char*)d_ws + 305152);

  prep_pack<<<528, 256, 0, stream>>>(W2, W3, b3, Wg2, W2f, b3f, b3c);
  fnn_fused<<<NBLK, 256, 0, stream>>>(pos_i, pos_j, vj, W1, b1, b2, W2f, Wg2, b3f, b3c, outp);
}